// Round 1
// baseline (570.335 us; speedup 1.0000x reference)
//
#include <hip/hip_runtime.h>

// Problem constants
#define OUT_F 4096   // compressed rows
#define IN_F  2048   // compressed cols
#define KLOG  4096   // logical k = 2*IN_F
#define NB    4096   // batch (n)
#define MLOG  8192   // logical m = 2*OUT_F

typedef __bf16 bf16x8 __attribute__((ext_vector_type(8)));
typedef short  s16x8  __attribute__((ext_vector_type(8)));
typedef float  f32x4  __attribute__((ext_vector_type(4)));

__device__ __forceinline__ unsigned short f2bf(float f) {
    // round-to-nearest-even fp32 -> bf16 (inputs are finite normals)
    unsigned int u = __float_as_uint(f);
    u += 0x7fffu + ((u >> 16) & 1u);
    return (unsigned short)(u >> 16);
}

// Block: 256 threads = 4 waves. Tile: 128 compressed rows x 128 batch cols.
// K-loop: BK=32 logical cols (= 16 compressed cols = 8 groups-of-4).
// Wave (wm,wn) owns a 64x64 quadrant = 4x4 grid of 16x16x32 MFMA tiles.
__global__ __launch_bounds__(256) void spmm_dt_kernel(
    const float* __restrict__ weight,
    const int*   __restrict__ indices,
    const int*   __restrict__ metadata,
    const float* __restrict__ input,
    float*       __restrict__ out)
{
    __shared__ __align__(16) unsigned short As[128][32]; // decompressed W tile (bf16 bits)
    __shared__ __align__(16) unsigned short Bs[128][32]; // input tile (bf16 bits)

    const int tid  = threadIdx.x;
    const int lane = tid & 63;
    const int wave = tid >> 6;
    const int wm   = wave >> 1;   // 0..1 row-quadrant
    const int wn   = wave & 1;    // 0..1 col-quadrant
    const int l15  = lane & 15;
    const int quad = lane >> 4;

    const int r0 = blockIdx.y * 128;  // compressed-row base
    const int b0 = blockIdx.x * 128;  // batch base

    f32x4 acc[4][4];
#pragma unroll
    for (int i = 0; i < 4; ++i)
#pragma unroll
        for (int j = 0; j < 4; ++j)
            acc[i][j] = (f32x4){0.f, 0.f, 0.f, 0.f};

    const int srow = tid >> 3;   // 0..31: staging row within a 32-row chunk
    const int sgrp = tid & 7;    // 0..7 : group (A) / float4 slot (B)

    for (int kk = 0; kk < KLOG / 32; ++kk) {
        const int c0 = kk * 16;  // compressed-col base (even)
        const int k0 = kk * 32;  // logical-col base

        // ---- stage A: decompress 2-of-4 groups into dense bf16 ----
#pragma unroll
        for (int s = 0; s < 4; ++s) {
            const int row = srow + s * 32;
            const int r   = r0 + row;
            const size_t off = (size_t)r * IN_F + c0 + 2 * sgrp;
            const float2 w  = *(const float2*)(weight + off);
            const int2   md = *(const int2*)(metadata + off);
            // distinct sorted positions md.x < md.y -> shift-OR builds 4 bf16 slots
            unsigned long long v =
                ((unsigned long long)f2bf(w.x) << (md.x * 16)) |
                ((unsigned long long)f2bf(w.y) << (md.y * 16));
            *(unsigned long long*)(&As[row][4 * sgrp]) = v;
        }

        // ---- stage B: input fp32 -> bf16 ----
#pragma unroll
        for (int s = 0; s < 4; ++s) {
            const int row = srow + s * 32;
            const float4 f = *(const float4*)(&input[(size_t)(b0 + row) * KLOG + k0 + sgrp * 4]);
            unsigned long long v =
                 (unsigned long long)f2bf(f.x)        |
                ((unsigned long long)f2bf(f.y) << 16) |
                ((unsigned long long)f2bf(f.z) << 32) |
                ((unsigned long long)f2bf(f.w) << 48);
            *(unsigned long long*)(&Bs[row][sgrp * 4]) = v;
        }

        __syncthreads();

        // ---- MFMA: a-frag lane = A[m=l15][k=quad*8..+7]; b-frag symmetric ----
        bf16x8 a[4], b[4];
#pragma unroll
        for (int i = 0; i < 4; ++i)
            a[i] = __builtin_bit_cast(bf16x8,
                     *(const s16x8*)(&As[wm * 64 + i * 16 + l15][quad * 8]));
#pragma unroll
        for (int j = 0; j < 4; ++j)
            b[j] = __builtin_bit_cast(bf16x8,
                     *(const s16x8*)(&Bs[wn * 64 + j * 16 + l15][quad * 8]));
#pragma unroll
        for (int i = 0; i < 4; ++i)
#pragma unroll
            for (int j = 0; j < 4; ++j)
                acc[i][j] = __builtin_amdgcn_mfma_f32_16x16x32_bf16(
                                a[i], b[j], acc[i][j], 0, 0, 0);

        __syncthreads();
    }

    // ---- epilogue: C/D layout row=quad*4+t, col=l15; scatter via indices,
    //      and zero the sibling logical row (indices[r]^1). Every output
    //      element is written exactly once across the grid. ----
#pragma unroll
    for (int i = 0; i < 4; ++i) {
#pragma unroll
        for (int t = 0; t < 4; ++t) {
            const int rloc = wm * 64 + i * 16 + quad * 4 + t;
            const int r    = r0 + rloc;
            const int L    = indices[r];
            const size_t base  = (size_t)L * NB;
            const size_t baseZ = (size_t)(L ^ 1) * NB;
#pragma unroll
            for (int j = 0; j < 4; ++j) {
                const int col = b0 + wn * 64 + j * 16 + l15;
                out[base  + col] = acc[i][j][t];
                out[baseZ + col] = 0.0f;
            }
        }
    }
}

extern "C" void kernel_launch(void* const* d_in, const int* in_sizes, int n_in,
                              void* d_out, int out_size, void* d_ws, size_t ws_size,
                              hipStream_t stream) {
    const float* weight   = (const float*)d_in[0];
    const int*   indices  = (const int*)d_in[1];
    const int*   metadata = (const int*)d_in[2];
    const float* input    = (const float*)d_in[3];
    float*       out      = (float*)d_out;

    dim3 grid(NB / 128, OUT_F / 128);  // 32 x 32 blocks
    spmm_dt_kernel<<<grid, dim3(256), 0, stream>>>(weight, indices, metadata, input, out);
}

// Round 2
// 416.810 us; speedup vs baseline: 1.3683x; 1.3683x over previous
//
#include <hip/hip_runtime.h>

#define OUT_F 4096   // compressed rows
#define IN_F  2048   // compressed cols
#define KLOG  4096   // logical k = 2*IN_F
#define NB    4096   // batch
typedef unsigned long long ull;

typedef __bf16 bf16x8 __attribute__((ext_vector_type(8)));
typedef short  s16x8  __attribute__((ext_vector_type(8)));
typedef float  f32x4  __attribute__((ext_vector_type(4)));

__device__ __forceinline__ unsigned short f2bf(float f) {
    unsigned int u = __float_as_uint(f);
    u += 0x7fffu + ((u >> 16) & 1u);
    return (unsigned short)(u >> 16);
}

__device__ __forceinline__ void gload_lds16(const void* g, void* l) {
    __builtin_amdgcn_global_load_lds(
        (const __attribute__((address_space(1))) unsigned int*)g,
        (__attribute__((address_space(3))) unsigned int*)l, 16, 0, 0);
}

// ---------- Pre-pass: decompress weight -> dense bf16 wsA[4096][4096];
//            convert input fp32 -> bf16 wsB[4096][4096]. One fused launch. ----------
__global__ __launch_bounds__(256) void prep_kernel(
    const float* __restrict__ weight, const int* __restrict__ metadata,
    const float* __restrict__ input,
    unsigned short* __restrict__ wsA, unsigned short* __restrict__ wsB)
{
    const int b = blockIdx.x;
    if (b < 8192) {
        // weight: each thread handles 4 compressed elems (= 2 groups-of-4 logical), writes 16B
        const int g = b * 256 + threadIdx.x;      // 0 .. 2M-1
        const int r = g >> 9;                     // / (2048/4)
        const int c = (g & 511) * 4;              // compressed col
        const float4 wv = *(const float4*)(weight   + (size_t)r * IN_F + c);
        const int4   mv = *(const int4*)  (metadata + (size_t)r * IN_F + c);
        ull v0 = ((ull)f2bf(wv.x) << (mv.x * 16)) | ((ull)f2bf(wv.y) << (mv.y * 16));
        ull v1 = ((ull)f2bf(wv.z) << (mv.z * 16)) | ((ull)f2bf(wv.w) << (mv.w * 16));
        ull* dst = (ull*)(wsA + (size_t)r * KLOG + 2 * c);  // logical col = 4*(c/2) = 2c
        dst[0] = v0; dst[1] = v1;
    } else {
        // input: each thread converts 8 fp32 -> 8 bf16 (16B store)
        const int g = (b - 8192) * 256 + threadIdx.x;
        const size_t off = (size_t)g * 8;
        const float4 f0 = *(const float4*)(input + off);
        const float4 f1 = *(const float4*)(input + off + 4);
        ull v0 =  (ull)f2bf(f0.x) | ((ull)f2bf(f0.y) << 16) |
                 ((ull)f2bf(f0.z) << 32) | ((ull)f2bf(f0.w) << 48);
        ull v1 =  (ull)f2bf(f1.x) | ((ull)f2bf(f1.y) << 16) |
                 ((ull)f2bf(f1.z) << 32) | ((ull)f2bf(f1.w) << 48);
        ull* dst = (ull*)(wsB + off);
        dst[0] = v0; dst[1] = v1;
    }
}

// ---------- Main GEMM (m97 structure): 128x128 tile, BK=32, 16x16x32 bf16 MFMA,
//            global_load_lds width=16 staging, scatter epilogue. ----------
__global__ __launch_bounds__(256) void gemm_kernel(
    const unsigned short* __restrict__ wsA, const unsigned short* __restrict__ wsB,
    const int* __restrict__ indices, float* __restrict__ out)
{
    __shared__ __align__(16) unsigned short As[128 * 32];
    __shared__ __align__(16) unsigned short Bs[128 * 32];

    const int tid  = threadIdx.x;
    const int lane = tid & 63;
    const int wave = tid >> 6;
    const int wm   = wave >> 1;
    const int wn   = wave & 1;
    const int l15  = lane & 15;
    const int quad = lane >> 4;

    const int r0 = blockIdx.y * 128;
    const int b0 = blockIdx.x * 128;

    // staging geometry: wave stages rows [wave*32, wave*32+32); two 1KB calls per tile.
    // LDS linear offset o = wave*2048 + call*1024 + lane*16  ->  row = o/64, colbyte = o%64
    const int srow  = wave * 32 + (lane >> 2);   // call 0 row; call 1 adds +16
    const int scolh = (lane & 3) * 8;            // ushort offset within row
    const unsigned ldsA0 = wave * 2048;          // byte offsets (wave-uniform)
    const unsigned short* gA = wsA + (size_t)(r0 + srow) * KLOG + scolh;
    const unsigned short* gB = wsB + (size_t)(b0 + srow) * KLOG + scolh;

    f32x4 acc[4][4];
#pragma unroll
    for (int i = 0; i < 4; ++i)
#pragma unroll
        for (int j = 0; j < 4; ++j)
            acc[i][j] = (f32x4){0.f, 0.f, 0.f, 0.f};

    for (int k0 = 0; k0 < KLOG; k0 += 32) {
        gload_lds16(gA + k0,             (char*)As + ldsA0);
        gload_lds16(gA + 16 * KLOG + k0, (char*)As + ldsA0 + 1024);
        gload_lds16(gB + k0,             (char*)Bs + ldsA0);
        gload_lds16(gB + 16 * KLOG + k0, (char*)Bs + ldsA0 + 1024);
        __syncthreads();

        bf16x8 a[4], b[4];
#pragma unroll
        for (int i = 0; i < 4; ++i)
            a[i] = __builtin_bit_cast(bf16x8,
                     *(const s16x8*)(As + (wm * 64 + i * 16 + l15) * 32 + quad * 8));
#pragma unroll
        for (int j = 0; j < 4; ++j)
            b[j] = __builtin_bit_cast(bf16x8,
                     *(const s16x8*)(Bs + (wn * 64 + j * 16 + l15) * 32 + quad * 8));
#pragma unroll
        for (int i = 0; i < 4; ++i)
#pragma unroll
            for (int j = 0; j < 4; ++j)
                acc[i][j] = __builtin_amdgcn_mfma_f32_16x16x32_bf16(
                                a[i], b[j], acc[i][j], 0, 0, 0);
        __syncthreads();
    }

    // epilogue: C/D row = quad*4+t, col = l15; scatter to indices[r], zero sibling row
#pragma unroll
    for (int i = 0; i < 4; ++i) {
#pragma unroll
        for (int t = 0; t < 4; ++t) {
            const int r = r0 + wm * 64 + i * 16 + quad * 4 + t;
            const int L = indices[r];
            const size_t base  = (size_t)L * NB;
            const size_t baseZ = (size_t)(L ^ 1) * NB;
#pragma unroll
            for (int j = 0; j < 4; ++j) {
                const int col = b0 + wn * 64 + j * 16 + l15;
                out[base  + col] = acc[i][j][t];
                out[baseZ + col] = 0.0f;
            }
        }
    }
}

// ---------- Fallback (round-1 fused kernel) if ws is too small ----------
__global__ __launch_bounds__(256) void spmm_dt_fallback(
    const float* __restrict__ weight, const int* __restrict__ indices,
    const int* __restrict__ metadata, const float* __restrict__ input,
    float* __restrict__ out)
{
    __shared__ __align__(16) unsigned short As[128][32];
    __shared__ __align__(16) unsigned short Bs[128][32];
    const int tid = threadIdx.x, lane = tid & 63, wave = tid >> 6;
    const int wm = wave >> 1, wn = wave & 1, l15 = lane & 15, quad = lane >> 4;
    const int r0 = blockIdx.y * 128, b0 = blockIdx.x * 128;
    f32x4 acc[4][4];
#pragma unroll
    for (int i = 0; i < 4; ++i)
#pragma unroll
        for (int j = 0; j < 4; ++j) acc[i][j] = (f32x4){0.f, 0.f, 0.f, 0.f};
    const int srow = tid >> 3, sgrp = tid & 7;
    for (int kk = 0; kk < KLOG / 32; ++kk) {
        const int c0 = kk * 16, k0 = kk * 32;
#pragma unroll
        for (int s = 0; s < 4; ++s) {
            const int row = srow + s * 32;
            const size_t off = (size_t)(r0 + row) * IN_F + c0 + 2 * sgrp;
            const float2 w = *(const float2*)(weight + off);
            const int2  md = *(const int2*)(metadata + off);
            *(ull*)(&As[row][4 * sgrp]) =
                ((ull)f2bf(w.x) << (md.x * 16)) | ((ull)f2bf(w.y) << (md.y * 16));
        }
#pragma unroll
        for (int s = 0; s < 4; ++s) {
            const int row = srow + s * 32;
            const float4 f = *(const float4*)(&input[(size_t)(b0 + row) * KLOG + k0 + sgrp * 4]);
            *(ull*)(&Bs[row][sgrp * 4]) =
                 (ull)f2bf(f.x) | ((ull)f2bf(f.y) << 16) |
                ((ull)f2bf(f.z) << 32) | ((ull)f2bf(f.w) << 48);
        }
        __syncthreads();
        bf16x8 a[4], b[4];
#pragma unroll
        for (int i = 0; i < 4; ++i)
            a[i] = __builtin_bit_cast(bf16x8, *(const s16x8*)(&As[wm * 64 + i * 16 + l15][quad * 8]));
#pragma unroll
        for (int j = 0; j < 4; ++j)
            b[j] = __builtin_bit_cast(bf16x8, *(const s16x8*)(&Bs[wn * 64 + j * 16 + l15][quad * 8]));
#pragma unroll
        for (int i = 0; i < 4; ++i)
#pragma unroll
            for (int j = 0; j < 4; ++j)
                acc[i][j] = __builtin_amdgcn_mfma_f32_16x16x32_bf16(a[i], b[j], acc[i][j], 0, 0, 0);
        __syncthreads();
    }
#pragma unroll
    for (int i = 0; i < 4; ++i)
#pragma unroll
        for (int t = 0; t < 4; ++t) {
            const int r = r0 + wm * 64 + i * 16 + quad * 4 + t;
            const int L = indices[r];
            const size_t base = (size_t)L * NB, baseZ = (size_t)(L ^ 1) * NB;
#pragma unroll
            for (int j = 0; j < 4; ++j) {
                const int col = b0 + wn * 64 + j * 16 + l15;
                out[base + col] = acc[i][j][t];
                out[baseZ + col] = 0.0f;
            }
        }
}

extern "C" void kernel_launch(void* const* d_in, const int* in_sizes, int n_in,
                              void* d_out, int out_size, void* d_ws, size_t ws_size,
                              hipStream_t stream) {
    const float* weight   = (const float*)d_in[0];
    const int*   indices  = (const int*)d_in[1];
    const int*   metadata = (const int*)d_in[2];
    const float* input    = (const float*)d_in[3];
    float*       out      = (float*)d_out;

    const size_t needA = (size_t)OUT_F * KLOG * 2;  // 32 MB
    const size_t needB = (size_t)NB * KLOG * 2;     // 32 MB
    if (ws_size >= needA + needB) {
        unsigned short* wsA = (unsigned short*)d_ws;
        unsigned short* wsB = wsA + (size_t)OUT_F * KLOG;
        prep_kernel<<<dim3(16384), dim3(256), 0, stream>>>(weight, metadata, input, wsA, wsB);
        gemm_kernel<<<dim3(NB / 128, OUT_F / 128), dim3(256), 0, stream>>>(wsA, wsB, indices, out);
    } else {
        spmm_dt_fallback<<<dim3(NB / 128, OUT_F / 128), dim3(256), 0, stream>>>(
            weight, indices, metadata, input, out);
    }
}